// Round 1
// baseline (539.867 us; speedup 1.0000x reference)
//
#include <hip/hip_runtime.h>

#define B_   16
#define CIN  32
#define COUT 32
#define HH   256
#define WW   256
#define NE   8

#define TILE_H 8
#define TILE_W 16
#define CHUNK  8

// ---------------------------------------------------------------------------
// Kernel A: mix expert weights per sample.
//   ws_w layout: [b][ci][tap][co]  (tap = kh*3+kw)  -> float4-aligned co reads
//   ws_b layout: [b][co]
// Reference layout: params idx = co*288 + ci*9 + tap
// ---------------------------------------------------------------------------
__global__ __launch_bounds__(256) void prep_weights(
    const float* __restrict__ routing,  // [16][8]
    const float* __restrict__ ew,       // [8][9216]
    const float* __restrict__ eb,       // [8][32]
    float* __restrict__ ws_w,           // [16][32][9][32]
    float* __restrict__ ws_b)           // [16][32]
{
    const int b = blockIdx.x;
    const int t = threadIdx.x;
    float r[NE];
#pragma unroll
    for (int e = 0; e < NE; ++e) r[e] = routing[b * NE + e];

    for (int idx = t; idx < COUT * CIN * 9; idx += 256) {
        int co  = idx / (CIN * 9);
        int rem = idx - co * (CIN * 9);
        int ci  = rem / 9;
        int tap = rem - ci * 9;
        float acc = 0.f;
#pragma unroll
        for (int e = 0; e < NE; ++e) acc += r[e] * ew[e * (COUT * CIN * 9) + idx];
        ws_w[((b * CIN + ci) * 9 + tap) * COUT + co] = acc;
    }
    if (t < COUT) {
        float acc = 0.f;
#pragma unroll
        for (int e = 0; e < NE; ++e) acc += r[e] * eb[e * COUT + t];
        ws_b[b * COUT + t] = acc;
    }
}

// ---------------------------------------------------------------------------
// Kernel B: direct conv, register-blocked.
// Block: 256 threads -> output tile [32co][8 rows][16 cols] for one batch.
// Thread: 4co x 4px micro-tile (16 accumulators).
//   t = cg*32 + pg ; cg in 0..7 (co = cg*4..cg*4+3)
//   pg -> pr = pg>>2 (row 0..7), pc = (pg&3)*4 (col 0,4,8,12)
// LDS per ci-chunk of 8: input (8+2)x(16+2) padded to row stride 20 (16B
// aligned), weights [8][9][32].
// ---------------------------------------------------------------------------
__global__ __launch_bounds__(256) void condconv(
    const float* __restrict__ x,     // [16][32][256][256]
    const float* __restrict__ ws_w,  // [16][32][9][32]
    const float* __restrict__ ws_b,  // [16][32]
    float* __restrict__ out)         // [16][32][256][256]
{
    __shared__ float s_in[CHUNK][TILE_H + 2][20];
    __shared__ float s_w[CHUNK][9][COUT];

    const int tx = blockIdx.x;          // 0..15
    const int ty = blockIdx.y;          // 0..31
    const int b  = blockIdx.z;          // 0..15
    const int x0 = tx * TILE_W;
    const int y0 = ty * TILE_H;

    const int t  = threadIdx.x;
    const int cg = t >> 5;              // 0..7
    const int pg = t & 31;
    const int pr = pg >> 2;             // 0..7
    const int pc = (pg & 3) * 4;        // 0,4,8,12

    float acc[4][4];
#pragma unroll
    for (int i = 0; i < 4; ++i)
#pragma unroll
        for (int j = 0; j < 4; ++j) acc[i][j] = 0.f;

    for (int c0 = 0; c0 < CIN; c0 += CHUNK) {
        __syncthreads();
        // stage input: CHUNK * 10 * 18 = 1440 elements
        for (int idx = t; idx < CHUNK * (TILE_H + 2) * 18; idx += 256) {
            int ci  = idx / ((TILE_H + 2) * 18);
            int rem = idx - ci * ((TILE_H + 2) * 18);
            int r   = rem / 18;
            int c   = rem - r * 18;
            int gy  = y0 + r - 1;
            int gx  = x0 + c - 1;
            float v = 0.f;
            if (gy >= 0 && gy < HH && gx >= 0 && gx < WW)
                v = x[((b * CIN + c0 + ci) * HH + gy) * WW + gx];
            s_in[ci][r][c] = v;
        }
        // stage weights: CHUNK*9*32 = 2304 consecutive floats
        const float* wsrc = ws_w + (b * CIN + c0) * 9 * COUT;
        for (int idx = t; idx < CHUNK * 9 * COUT; idx += 256)
            (&s_w[0][0][0])[idx] = wsrc[idx];
        __syncthreads();

#pragma unroll
        for (int ci = 0; ci < CHUNK; ++ci) {
            float in[3][6];
#pragma unroll
            for (int r = 0; r < 3; ++r)
#pragma unroll
                for (int c = 0; c < 6; ++c)
                    in[r][c] = s_in[ci][pr + r][pc + c];

#pragma unroll
            for (int dy = 0; dy < 3; ++dy)
#pragma unroll
                for (int dx = 0; dx < 3; ++dx) {
                    const float4 w4 =
                        *(const float4*)&s_w[ci][dy * 3 + dx][cg * 4];
#pragma unroll
                    for (int j = 0; j < 4; ++j) {
                        const float iv = in[dy][dx + j];
                        acc[0][j] += w4.x * iv;
                        acc[1][j] += w4.y * iv;
                        acc[2][j] += w4.z * iv;
                        acc[3][j] += w4.w * iv;
                    }
                }
        }
    }

    // epilogue: add bias, coalesced float4 stores
#pragma unroll
    for (int i = 0; i < 4; ++i) {
        const int co = cg * 4 + i;
        const float bias = ws_b[b * COUT + co];
        float4 v = make_float4(acc[i][0] + bias, acc[i][1] + bias,
                               acc[i][2] + bias, acc[i][3] + bias);
        *(float4*)&out[((b * COUT + co) * HH + (y0 + pr)) * WW + (x0 + pc)] = v;
    }
}

extern "C" void kernel_launch(void* const* d_in, const int* in_sizes, int n_in,
                              void* d_out, int out_size, void* d_ws, size_t ws_size,
                              hipStream_t stream) {
    const float* x       = (const float*)d_in[0];
    const float* routing = (const float*)d_in[1];
    const float* ew      = (const float*)d_in[2];
    const float* eb      = (const float*)d_in[3];
    float* out = (float*)d_out;

    float* ws_w = (float*)d_ws;                              // 16*32*9*32 floats
    float* ws_b = ws_w + B_ * CIN * 9 * COUT;                // 16*32 floats

    prep_weights<<<dim3(B_), dim3(256), 0, stream>>>(routing, ew, eb, ws_w, ws_b);

    dim3 grid(WW / TILE_W, HH / TILE_H, B_);                 // (16, 32, 16)
    condconv<<<grid, dim3(256), 0, stream>>>(x, ws_w, ws_b, out);
}

// Round 2
// 274.785 us; speedup vs baseline: 1.9647x; 1.9647x over previous
//
#include <hip/hip_runtime.h>

#define B_   16
#define CIN  32
#define COUT 32
#define HH   256
#define WW   256
#define NE   8
#define NTAP 9
#define KTOT (NTAP * CIN)   // 288

#define TH 8
#define TW 64
#define LROWS (TH + 2)      // 10
#define LCOLS (TW + 2)      // 66
#define PXS   40            // ushorts per pixel: 32 data + 8 pad = 80 B (bank spread)

typedef __attribute__((ext_vector_type(8))) short  short8;   // 8 bf16 = 4 VGPRs
typedef __attribute__((ext_vector_type(4))) float  floatx4;  // MFMA C/D

// fp32 -> bf16, round-to-nearest-even
__device__ __forceinline__ unsigned short f2bf(float f) {
    unsigned int u = __float_as_uint(f);
    u += 0x7FFFu + ((u >> 16) & 1u);
    return (unsigned short)(u >> 16);
}

// ---------------------------------------------------------------------------
// Mix expert weights per sample -> bf16, layout [b][co][k = tap*32 + ci].
// Reference weight flat index: co*288 + ci*9 + tap.
// ---------------------------------------------------------------------------
__global__ __launch_bounds__(256) void prep_weights(
    const float* __restrict__ routing,   // [16][8]
    const float* __restrict__ ew,        // [8][9216]
    const float* __restrict__ eb,        // [8][32]
    unsigned short* __restrict__ ws_w,   // [16][32][288] bf16 bits
    float* __restrict__ ws_b)            // [16][32]
{
    const int b = blockIdx.x;
    const int t = threadIdx.x;
    float r[NE];
#pragma unroll
    for (int e = 0; e < NE; ++e) r[e] = routing[b * NE + e];

    for (int idx = t; idx < COUT * KTOT; idx += 256) {
        const int co  = idx / KTOT;
        const int k   = idx - co * KTOT;
        const int tap = k >> 5;          // k / 32
        const int ci  = k & 31;
        float acc = 0.f;
#pragma unroll
        for (int e = 0; e < NE; ++e)
            acc += r[e] * ew[e * (COUT * CIN * 9) + co * (CIN * 9) + ci * 9 + tap];
        ws_w[(b * COUT + co) * KTOT + k] = f2bf(acc);
    }
    if (t < COUT) {
        float acc = 0.f;
#pragma unroll
        for (int e = 0; e < NE; ++e) acc += r[e] * eb[e * COUT + t];
        ws_b[b * COUT + t] = acc;
    }
}

// ---------------------------------------------------------------------------
// Implicit-GEMM conv. Block = 256 thr (4 waves), one 8x64 output tile / batch b.
// LDS: x tile in [pixel][ci] bf16, pixel stride 80 B. Single barrier.
// Wave: 8 sub-tiles of 16 px; per tap: 1 ds_read_b128 (B) + 2 MFMA (co halves).
// ---------------------------------------------------------------------------
__global__ __launch_bounds__(256) void condconv_mfma(
    const float* __restrict__ x,             // [16][32][256][256] fp32
    const unsigned short* __restrict__ wsw,  // [16][32][288] bf16
    const float* __restrict__ wsb,           // [16][32]
    float* __restrict__ out)                 // [16][32][256][256] fp32
{
    __shared__ __align__(16) unsigned short s_x[LROWS * LCOLS * PXS];  // 52.8 KB

    const int b    = blockIdx.z;
    const int x0   = blockIdx.x * TW;
    const int y0   = blockIdx.y * TH;
    const int t    = threadIdx.x;
    const int lane = t & 63;
    const int wv   = t >> 6;        // wave 0..3
    const int ln   = lane & 15;     // MFMA n / m-within-half
    const int quad = lane >> 4;     // MFMA k-group / row-group

    // --- preload A fragments (weights) + bias: latency hides behind staging ---
    short8 afrag[NTAP][2];
    {
        const unsigned short* wb = wsw + (size_t)b * COUT * KTOT;
#pragma unroll
        for (int tap = 0; tap < NTAP; ++tap)
#pragma unroll
            for (int h = 0; h < 2; ++h)
                afrag[tap][h] = *(const short8*)(wb + (h * 16 + ln) * KTOT + tap * 32 + quad * 8);
    }
    float bias_v[2][4];
#pragma unroll
    for (int h = 0; h < 2; ++h)
#pragma unroll
        for (int rg = 0; rg < 4; ++rg)
            bias_v[h][rg] = wsb[b * COUT + h * 16 + quad * 4 + rg];

    // --- stage input tile: fp32 NCHW global -> bf16 [pixel][ci] LDS ---
    // task = pixel * 4 + ci_chunk; each task: 8 coalesced plane reads -> 1 b128 write
    for (int task = t; task < LROWS * LCOLS * 4; task += 256) {
        const int p   = task >> 2;
        const int c   = task & 3;
        const int row = p / LCOLS;
        const int col = p - row * LCOLS;
        const int gy  = y0 + row - 1;
        const int gx  = x0 + col - 1;
        short8 pk;
        if (gy >= 0 && gy < HH && gx >= 0 && gx < WW) {
            const float* src = x + (((size_t)b * CIN + c * 8) * HH + gy) * WW + gx;
#pragma unroll
            for (int u = 0; u < 8; ++u)
                pk[u] = (short)f2bf(src[(size_t)u * HH * WW]);
        } else {
#pragma unroll
            for (int u = 0; u < 8; ++u) pk[u] = 0;
        }
        *(short8*)&s_x[p * PXS + c * 8] = pk;
    }
    __syncthreads();

    // --- K loop: 9 taps x 8 sub-tiles x 2 co-halves ---
    floatx4 acc[8][2];
#pragma unroll
    for (int tt = 0; tt < 8; ++tt)
#pragma unroll
        for (int h = 0; h < 2; ++h)
            acc[tt][h] = (floatx4){0.f, 0.f, 0.f, 0.f};

#pragma unroll
    for (int tap = 0; tap < NTAP; ++tap) {
        const int dy = tap / 3;
        const int dx = tap - dy * 3;
#pragma unroll
        for (int tt = 0; tt < 8; ++tt) {
            const int r    = 2 * wv + (tt >> 2);
            const int q    = tt & 3;
            const int lrow = r + dy;
            const int lcol = q * 16 + ln + dx;
            const short8 bfr = *(const short8*)&s_x[(lrow * LCOLS + lcol) * PXS + quad * 8];
            acc[tt][0] = __builtin_amdgcn_mfma_f32_16x16x32_bf16(afrag[tap][0], bfr, acc[tt][0], 0, 0, 0);
            acc[tt][1] = __builtin_amdgcn_mfma_f32_16x16x32_bf16(afrag[tap][1], bfr, acc[tt][1], 0, 0, 0);
        }
    }

    // --- epilogue: bias + coalesced (64B-segment) stores ---
#pragma unroll
    for (int tt = 0; tt < 8; ++tt) {
        const int r  = 2 * wv + (tt >> 2);
        const int q  = tt & 3;
        const int gy = y0 + r;
        const int gx = x0 + q * 16 + ln;
#pragma unroll
        for (int h = 0; h < 2; ++h)
#pragma unroll
            for (int rg = 0; rg < 4; ++rg) {
                const int co = h * 16 + quad * 4 + rg;
                out[(((size_t)b * COUT + co) * HH + gy) * WW + gx] = acc[tt][h][rg] + bias_v[h][rg];
            }
    }
}

extern "C" void kernel_launch(void* const* d_in, const int* in_sizes, int n_in,
                              void* d_out, int out_size, void* d_ws, size_t ws_size,
                              hipStream_t stream) {
    const float* x       = (const float*)d_in[0];
    const float* routing = (const float*)d_in[1];
    const float* ew      = (const float*)d_in[2];
    const float* eb      = (const float*)d_in[3];
    float* out = (float*)d_out;

    unsigned short* ws_w = (unsigned short*)d_ws;            // 16*32*288 bf16 = 294912 B
    float* ws_b = (float*)((char*)d_ws + (size_t)B_ * COUT * KTOT * 2);

    prep_weights<<<dim3(B_), dim3(256), 0, stream>>>(routing, ew, eb, ws_w, ws_b);

    dim3 grid(WW / TW, HH / TH, B_);                         // (4, 32, 16)
    condconv_mfma<<<grid, dim3(256), 0, stream>>>(x, ws_w, ws_b, out);
}